// Round 3
// baseline (13430.568 us; speedup 1.0000x reference)
//
#include <hip/hip_runtime.h>
#include <cstdint>
#include <cstddef>

// ---------------------------------------------------------------------------
// FieldLstmEncoder on MI355X (gfx950)   B=128 S=512 UNI=512 HID=1024 FLD=128
// PERSISTENT v2: 128 blocks x 512 thr. Block nb owns 8 H-cols [8nb,8nb+8)
// across all 4 gates (32 gate-rows, two 16-col MFMA N-tiles). W1/W2 fragments
// staged ONCE in LDS in per-lane fragment order (zero bank conflicts).
// Waves 0-3: main GEMM (2 row-tiles x 2 N-tiles each, B-frag reuse).
// Waves 4-7: field GEMM. c/h in registers; h exchanged via global bf16 with
// one release + one acquire agent fence per step; tree grid barrier.
// ---------------------------------------------------------------------------

typedef __bf16 bf16;
typedef __bf16 bf16x2 __attribute__((ext_vector_type(2)));
typedef __bf16 bf16x8 __attribute__((ext_vector_type(8)));
typedef float floatx4 __attribute__((ext_vector_type(4)));

#define B_ 128
#define S_ 512
#define UNI_ 512
#define HID_ 1024
#define FLD_ 128
#define K1_ 1536
#define NBLK 128
#define NSLOT 64

#if __has_builtin(__builtin_amdgcn_fence)
#define FENCE_REL() __builtin_amdgcn_fence(__ATOMIC_RELEASE, "agent")
#define FENCE_ACQ() __builtin_amdgcn_fence(__ATOMIC_ACQUIRE, "agent")
#else
#define FENCE_REL() __threadfence()
#define FENCE_ACQ() __threadfence()
#endif

__device__ __forceinline__ float sigf(float x) { return 1.0f / (1.0f + __expf(-x)); }

// ---------------------------------------------------------------------------
__global__ __launch_bounds__(128) void sort_kernel(const int* __restrict__ len,
                                                   int* __restrict__ perm,
                                                   int* __restrict__ lens) {
  int i = threadIdx.x;  // 128 threads, 1 block
  int li = len[i];
  int r = 0;
  for (int j = 0; j < B_; ++j) {
    int lj = len[j];
    r += (lj > li) || (lj == li && j < i) ? 1 : 0;
  }
  perm[r] = i;
  lens[r] = li;
}

__global__ __launch_bounds__(256) void conv_w(const float* __restrict__ W1,
                                              const float* __restrict__ W2,
                                              bf16* __restrict__ W1b,
                                              bf16* __restrict__ W2b) {
  int i = blockIdx.x * 256 + threadIdx.x;
  if (i < 4096 * K1_) W1b[i] = (bf16)W1[i];
  else {
    int j = i - 4096 * K1_;
    if (j < 2048 * FLD_) W2b[j] = (bf16)W2[j];
  }
}

// zero h double-buffer + barrier state (re-zeroed every launch: graph replay)
__global__ __launch_bounds__(256) void zero_state(bf16* __restrict__ h0,
                                                  bf16* __restrict__ h1,
                                                  int* __restrict__ bar) {
  int i = blockIdx.x * 256 + threadIdx.x;  // 131072
  h0[i] = (bf16)0.0f;
  h1[i] = (bf16)0.0f;
  if (i < 4096) bar[i] = 0;
}

// x,f fp32 -> bf16, rows permuted to sorted order, layout [t][rs][*].
__global__ __launch_bounds__(256) void conv_xf(const float* __restrict__ x,
                                               const float* __restrict__ f,
                                               const int* __restrict__ perm,
                                               bf16* __restrict__ xbf,
                                               bf16* __restrict__ fbf) {
  int t = blockIdx.x, rs = blockIdx.y, tid = threadIdx.x;
  int b = perm[rs];
  const float* xs = x + ((size_t)b * S_ + t) * UNI_;
  bf16* xd = xbf + ((size_t)t * B_ + rs) * UNI_;
  xd[tid] = (bf16)xs[tid];
  xd[tid + 256] = (bf16)xs[tid + 256];
  if (tid < FLD_) {
    fbf[((size_t)t * B_ + rs) * FLD_ + tid] =
        (bf16)f[((size_t)b * S_ + t) * FLD_ + tid];
  }
}

// zero out[b][t][:] for t >= len[b]. grid (S, B), 256 thr x float4.
__global__ __launch_bounds__(256) void zero_tail(const int* __restrict__ len,
                                                 float* __restrict__ out) {
  int t = blockIdx.x, b = blockIdx.y;
  if (t < len[b]) return;
  float4 z = {0.0f, 0.0f, 0.0f, 0.0f};
  float4* o = (float4*)(out + ((size_t)b * S_ + t) * HID_);
  o[threadIdx.x] = z;
}

// ---------------------------------------------------------------------------
// Tree grid barrier (128 blocks): 8 L1 counters (16 blocks each) -> L2 counter
// -> 64 release slots. Exactly one REL fence before arrive, one ACQ after.
// bar layout (ints): L1[g] at g*32 (g<8); L2 at 256; slots at 288 + s*32.
// ---------------------------------------------------------------------------
__device__ __forceinline__ void grid_barrier(int* __restrict__ bar, int t) {
  __syncthreads();
  if (threadIdx.x == 0) {
    FENCE_REL();  // drain + writeback L2: h/out stores visible at L3
    const int g = blockIdx.x >> 4;
    int p1 = __hip_atomic_fetch_add(bar + g * 32, 1, __ATOMIC_RELAXED,
                                    __HIP_MEMORY_SCOPE_AGENT);
    bool released = false;
    if (p1 == 15) {
      int p2 = __hip_atomic_fetch_add(bar + 256, 1, __ATOMIC_RELAXED,
                                      __HIP_MEMORY_SCOPE_AGENT);
      if (p2 == 7) {
        // all 128 arrived: reset counters, THEN release (ordered by waitcnt)
#pragma unroll
        for (int g2 = 0; g2 < 8; ++g2)
          __hip_atomic_store(bar + g2 * 32, 0, __ATOMIC_RELAXED,
                             __HIP_MEMORY_SCOPE_AGENT);
        __hip_atomic_store(bar + 256, 0, __ATOMIC_RELAXED,
                           __HIP_MEMORY_SCOPE_AGENT);
        __builtin_amdgcn_s_waitcnt(0);  // zeros committed before slot release
#pragma unroll
        for (int s = 0; s < NSLOT; ++s)
          __hip_atomic_store(bar + 288 + s * 32, t + 1, __ATOMIC_RELAXED,
                             __HIP_MEMORY_SCOPE_AGENT);
        released = true;
      }
    }
    if (!released) {
      int* my = bar + 288 + (blockIdx.x & (NSLOT - 1)) * 32;
      while (__hip_atomic_load(my, __ATOMIC_RELAXED,
                               __HIP_MEMORY_SCOPE_AGENT) <= t)
        __builtin_amdgcn_s_sleep(1);
    }
    FENCE_ACQ();  // invalidate L2: fresh h reads come from L3
  }
  __syncthreads();
}

// ---------------------------------------------------------------------------
// Persistent LSTM kernel: all 512 timesteps.
// ---------------------------------------------------------------------------
__global__ __launch_bounds__(512, 2) void lstm_persistent(
    const bf16* __restrict__ xbf,     // [S][128][UNI] sorted rows
    const bf16* __restrict__ fbf,     // [S][128][FLD] sorted rows
    const bf16* __restrict__ W1b,     // [4H][K1]
    const bf16* __restrict__ W2b,     // [2H][FLD]
    const float* __restrict__ bias1,  // [4H]
    const float* __restrict__ bias2,  // [2H]
    bf16* __restrict__ ha,            // [128][HID] h buffer (even t reads)
    bf16* __restrict__ hb,            // [128][HID] h buffer (odd t reads)
    const int* __restrict__ perm_g,   // [128] sorted -> orig
    const int* __restrict__ lens_g,   // [128] sorted desc
    float* __restrict__ out,
    int* __restrict__ bar) {
  // B-fragments in per-lane read order: BsF[nt][s][lane] (16B each) -> a wave's
  // ds_read_b128 is lane-contiguous (stride-1, ZERO bank conflicts).
  __shared__ bf16 BsF[2 * 48 * 64 * 8];  // 98304 B  W1 frags, staged once
  __shared__ bf16 Bs2[4 * 64 * 8];       //  4096 B  W2 frags, staged once
  __shared__ float pre_s[128][33];       // 16896 B  [row][gate*8+col]
  __shared__ float rd_s[128][17];        //  8704 B  [row][gate2*8+col]
  __shared__ int lens_s[128];
  __shared__ int perm_s[128];
  // total 129,024 B -> 1 block/CU (160 KiB pool); grid 128 <= 256 CUs

  const int tid = threadIdx.x;
  const int nb = blockIdx.x;

  // ---- one-time staging: W1 fragments (gate-row gr = gate*8+col) ----
  for (int i = tid; i < 2 * 48 * 64; i += 512) {
    int nt = i / (48 * 64);
    int r = i - nt * (48 * 64);
    int s = r >> 6, lane = r & 63;
    int gr = nt * 16 + (lane & 15);
    int wrow = (gr >> 3) * HID_ + nb * 8 + (gr & 7);
    int k = s * 32 + (lane >> 4) * 8;
    *(bf16x8*)(BsF + (size_t)i * 8) = *(const bf16x8*)(W1b + (size_t)wrow * K1_ + k);
  }
  if (tid < 256) {  // W2 fragments (16 gate2-rows)
    int s = tid >> 6, lane = tid & 63;
    int n = lane & 15;
    int w2row = (n >> 3) * HID_ + nb * 8 + (n & 7);
    int k = s * 32 + (lane >> 4) * 8;
    *(bf16x8*)(Bs2 + (size_t)tid * 8) = *(const bf16x8*)(W2b + (size_t)w2row * FLD_ + k);
  }
  if (tid < 128) {
    lens_s[tid] = lens_g[tid];
    perm_s[tid] = perm_g[tid];
  }
  __syncthreads();

  // ---- per-thread compute-phase constants ----
  const int wave = tid >> 6;
  const int lane = tid & 63;
  const int quad = lane >> 4;
  const int l16 = lane & 15;
  const int kq = quad * 8;
  const bool is_main = wave < 4;
  const int rg = is_main ? wave : (wave - 4);   // row group: rows [rg*32, rg*32+32)
  const int arow = rg * 32 + l16;               // tile0 row; tile1 = +16
  const int wlen = lens_s[rg * 32];             // lens sorted desc -> group max
  const bf16* bp = BsF + (size_t)lane * 8;      // + (nt*48+s)*512
  const bf16* b2p = Bs2 + (size_t)lane * 8;     // + s*512

  // ---- update-phase mapping: thread -> (row, 2 adjacent cols) ----
  const int urow = tid >> 2;
  const int p = tid & 3;
  const int cc0 = 2 * p;          // cols within block 0..7 (pair cc0, cc0+1)
  const int ucol = nb * 8 + cc0;  // global H col
  const float b1i0 = bias1[ucol], b1i1 = bias1[ucol + 1];
  const float b1j0 = bias1[HID_ + ucol], b1j1 = bias1[HID_ + ucol + 1];
  const float b1f0 = bias1[2 * HID_ + ucol], b1f1 = bias1[2 * HID_ + ucol + 1];
  const float b1o0 = bias1[3 * HID_ + ucol], b1o1 = bias1[3 * HID_ + ucol + 1];
  const float b2r0 = bias2[ucol], b2r1 = bias2[ucol + 1];
  const float b2d0 = bias2[HID_ + ucol], b2d1 = bias2[HID_ + ucol + 1];
  const int ulen = lens_s[urow];
  const size_t hidx = (size_t)urow * HID_ + ucol;
  float* outp = out + (size_t)perm_s[urow] * (S_ * HID_) + ucol;

  float c0v = 0.0f, c1v = 0.0f;  // cell state (registers; thread-owned)
  float h0v = 0.0f, h1v = 0.0f;  // hidden state fp32 masters

  for (int t = 0; t < S_; ++t) {
    const bf16* hcur = (t & 1) ? hb : ha;
    bf16* hnxt = (t & 1) ? ha : hb;

    if (t < wlen) {
      if (is_main) {
        floatx4 a00 = {0.f, 0.f, 0.f, 0.f};
        floatx4 a01 = {0.f, 0.f, 0.f, 0.f};
        floatx4 a10 = {0.f, 0.f, 0.f, 0.f};
        floatx4 a11 = {0.f, 0.f, 0.f, 0.f};
        const bf16* xp = xbf + ((size_t)t * B_ + arow) * UNI_ + kq;
        const bf16* hp = hcur + (size_t)arow * HID_ + kq;
        // K in [0,512): A = x_t
#pragma unroll
        for (int s = 0; s < 16; ++s) {
          bf16x8 a0 = *(const bf16x8*)(xp + s * 32);
          bf16x8 a1 = *(const bf16x8*)(xp + 16 * UNI_ + s * 32);
          bf16x8 b0 = *(const bf16x8*)(bp + (size_t)s * 512);
          bf16x8 b1 = *(const bf16x8*)(bp + (size_t)(48 + s) * 512);
          a00 = __builtin_amdgcn_mfma_f32_16x16x32_bf16(a0, b0, a00, 0, 0, 0);
          a01 = __builtin_amdgcn_mfma_f32_16x16x32_bf16(a0, b1, a01, 0, 0, 0);
          a10 = __builtin_amdgcn_mfma_f32_16x16x32_bf16(a1, b0, a10, 0, 0, 0);
          a11 = __builtin_amdgcn_mfma_f32_16x16x32_bf16(a1, b1, a11, 0, 0, 0);
        }
        // K in [512,1536): A = h_prev
#pragma unroll 8
        for (int s = 0; s < 32; ++s) {
          bf16x8 a0 = *(const bf16x8*)(hp + s * 32);
          bf16x8 a1 = *(const bf16x8*)(hp + 16 * HID_ + s * 32);
          bf16x8 b0 = *(const bf16x8*)(bp + (size_t)(16 + s) * 512);
          bf16x8 b1 = *(const bf16x8*)(bp + (size_t)(64 + s) * 512);
          a00 = __builtin_amdgcn_mfma_f32_16x16x32_bf16(a0, b0, a00, 0, 0, 0);
          a01 = __builtin_amdgcn_mfma_f32_16x16x32_bf16(a0, b1, a01, 0, 0, 0);
          a10 = __builtin_amdgcn_mfma_f32_16x16x32_bf16(a1, b0, a10, 0, 0, 0);
          a11 = __builtin_amdgcn_mfma_f32_16x16x32_bf16(a1, b1, a11, 0, 0, 0);
        }
        // C/D layout: col=l16, row=quad*4+r
        const int r0 = rg * 32 + quad * 4;
#pragma unroll
        for (int r = 0; r < 4; ++r) {
          pre_s[r0 + r][l16] = a00[r];
          pre_s[r0 + r][16 + l16] = a01[r];
          pre_s[r0 + 16 + r][l16] = a10[r];
          pre_s[r0 + 16 + r][16 + l16] = a11[r];
        }
      } else {
        // field GEMM: rd = f_t @ W2^T  (16 gate2-rows, K=128)
        floatx4 f0 = {0.f, 0.f, 0.f, 0.f};
        floatx4 f1 = {0.f, 0.f, 0.f, 0.f};
        const bf16* fp = fbf + ((size_t)t * B_ + arow) * FLD_ + kq;
#pragma unroll
        for (int s = 0; s < 4; ++s) {
          bf16x8 a0 = *(const bf16x8*)(fp + s * 32);
          bf16x8 a1 = *(const bf16x8*)(fp + 16 * FLD_ + s * 32);
          bf16x8 b = *(const bf16x8*)(b2p + (size_t)s * 512);
          f0 = __builtin_amdgcn_mfma_f32_16x16x32_bf16(a0, b, f0, 0, 0, 0);
          f1 = __builtin_amdgcn_mfma_f32_16x16x32_bf16(a1, b, f1, 0, 0, 0);
        }
        const int r0 = rg * 32 + quad * 4;
#pragma unroll
        for (int r = 0; r < 4; ++r) {
          rd_s[r0 + r][l16] = f0[r];
          rd_s[r0 + 16 + r][l16] = f1[r];
        }
      }
    }
    __syncthreads();

    // ---- LSTM elementwise update (c, h in registers; 2 cols/thread) ----
    if (t < ulen) {
      float iv0 = pre_s[urow][cc0] + b1i0, iv1 = pre_s[urow][cc0 + 1] + b1i1;
      float jv0 = pre_s[urow][8 + cc0] + b1j0, jv1 = pre_s[urow][9 + cc0] + b1j1;
      float fv0 = pre_s[urow][16 + cc0] + b1f0, fv1 = pre_s[urow][17 + cc0] + b1f1;
      float ov0 = pre_s[urow][24 + cc0] + b1o0, ov1 = pre_s[urow][25 + cc0] + b1o1;
      float rv0 = rd_s[urow][cc0] + b2r0, rv1 = rd_s[urow][cc0 + 1] + b2r1;
      float dv0 = rd_s[urow][8 + cc0] + b2d0, dv1 = rd_s[urow][9 + cc0] + b2d1;
      c0v = sigf(fv0 + 1.0f) * c0v + sigf(iv0) * tanhf(jv0) + sigf(rv0) * tanhf(dv0);
      c1v = sigf(fv1 + 1.0f) * c1v + sigf(iv1) * tanhf(jv1) + sigf(rv1) * tanhf(dv1);
      h0v = sigf(ov0) * tanhf(c0v);
      h1v = sigf(ov1) * tanhf(c1v);
      float2 o2;
      o2.x = h0v;
      o2.y = h1v;
      *(float2*)(outp + (size_t)t * HID_) = o2;
    }
    // unconditional: keeps frozen rows' h present in both ping-pong buffers
    bf16x2 hh = {(bf16)h0v, (bf16)h1v};
    *(bf16x2*)(hnxt + hidx) = hh;

    grid_barrier(bar, t);  // h fully visible chip-wide before t+1
  }

  // ---- final h, c tails (fp32 masters from registers) ----
  {
    const size_t base = (size_t)B_ * S_ * HID_;
    const size_t prow = (size_t)perm_s[urow] * HID_ + ucol;
    float2 hv, cv;
    hv.x = h0v;
    hv.y = h1v;
    cv.x = c0v;
    cv.y = c1v;
    *(float2*)(out + base + prow) = hv;
    *(float2*)(out + base + (size_t)B_ * HID_ + prow) = cv;
  }
}

// ---------------------------------------------------------------------------
extern "C" void kernel_launch(void* const* d_in, const int* in_sizes, int n_in,
                              void* d_out, int out_size, void* d_ws, size_t ws_size,
                              hipStream_t stream) {
  const float* x = (const float*)d_in[0];
  const float* f = (const float*)d_in[1];
  const int* len = (const int*)d_in[2];
  const float* W1 = (const float*)d_in[3];
  const float* b1 = (const float*)d_in[4];
  const float* W2 = (const float*)d_in[5];
  const float* b2 = (const float*)d_in[6];
  float* out = (float*)d_out;

  char* ws = (char*)d_ws;
  bf16* W1b = (bf16*)(ws);                    // 12,582,912
  bf16* W2b = (bf16*)(ws + 12582912);         //    524,288
  bf16* xbf = (bf16*)(ws + 13107200);         // 67,108,864  [S][B][UNI]
  bf16* fbf = (bf16*)(ws + 80216064);         // 16,777,216  [S][B][FLD]
  bf16* h0 = (bf16*)(ws + 96993280);          //    262,144
  bf16* h1 = (bf16*)(ws + 97255424);          //    262,144
  int* perm = (int*)(ws + 97517568);          //        512
  int* lens = (int*)(ws + 97518080);          //        512
  int* bar = (int*)(ws + 97518592);           //     16,384 (4096 ints)
  // total ~97.5 MB

  sort_kernel<<<1, 128, 0, stream>>>(len, perm, lens);
  conv_w<<<(4096 * K1_ + 2048 * FLD_ + 255) / 256, 256, 0, stream>>>(W1, W2, W1b, W2b);
  zero_state<<<512, 256, 0, stream>>>(h0, h1, bar);
  conv_xf<<<dim3(S_, B_), 256, 0, stream>>>(x, f, perm, xbf, fbf);
  zero_tail<<<dim3(S_, B_), 256, 0, stream>>>(len, out);

  lstm_persistent<<<NBLK, 512, 0, stream>>>(xbf, fbf, W1b, W2b, b1, b2, h0, h1,
                                            perm, lens, out, bar);
}

// Round 4
// 10424.552 us; speedup vs baseline: 1.2884x; 1.2884x over previous
//
#include <hip/hip_runtime.h>
#include <cstdint>
#include <cstddef>

// ---------------------------------------------------------------------------
// FieldLstmEncoder on MI355X (gfx950)   B=128 S=512 UNI=512 HID=1024 FLD=128
// PERSISTENT v3: 256 blocks x 512 thr (1 block/CU, full chip).
// Block = (rb, cb): rows [rb*64, rb*64+64), H-cols [cb*8, cb*8+8) over 4 gates
// (32 gate-cols = 2 MFMA N-tiles). Wave w: row-tile rt=w&3, N-tile nt=w>>2.
// NO cache fences: h exchanged via agent-scope relaxed atomics (sc0 sc1,
// L2-bypass, L3-coherent); x/f/W use normal L2-cached loads. Tree barrier
// with relaxed atomics only; writers drain with s_waitcnt vmcnt(0).
// ---------------------------------------------------------------------------

typedef __bf16 bf16;
typedef __bf16 bf16x8 __attribute__((ext_vector_type(8)));
typedef float floatx4 __attribute__((ext_vector_type(4)));
typedef unsigned long long u64;
typedef u64 u64x2 __attribute__((ext_vector_type(2)));

#define B_ 128
#define S_ 512
#define UNI_ 512
#define HID_ 1024
#define FLD_ 128
#define K1_ 1536
#define NBLK 256
#define NSLOT 64

__device__ __forceinline__ float sigf(float x) { return 1.0f / (1.0f + __expf(-x)); }

// ---------------------------------------------------------------------------
__global__ __launch_bounds__(128) void sort_kernel(const int* __restrict__ len,
                                                   int* __restrict__ perm,
                                                   int* __restrict__ lens) {
  int i = threadIdx.x;  // 128 threads, 1 block
  int li = len[i];
  int r = 0;
  for (int j = 0; j < B_; ++j) {
    int lj = len[j];
    r += (lj > li) || (lj == li && j < i) ? 1 : 0;
  }
  perm[r] = i;
  lens[r] = li;
}

__global__ __launch_bounds__(256) void conv_w(const float* __restrict__ W1,
                                              const float* __restrict__ W2,
                                              bf16* __restrict__ W1b,
                                              bf16* __restrict__ W2b) {
  int i = blockIdx.x * 256 + threadIdx.x;
  if (i < 4096 * K1_) W1b[i] = (bf16)W1[i];
  else {
    int j = i - 4096 * K1_;
    if (j < 2048 * FLD_) W2b[j] = (bf16)W2[j];
  }
}

// zero h double-buffer + barrier state (re-zeroed every launch: graph replay)
__global__ __launch_bounds__(256) void zero_state(bf16* __restrict__ h0,
                                                  bf16* __restrict__ h1,
                                                  int* __restrict__ bar) {
  int i = blockIdx.x * 256 + threadIdx.x;  // 131072
  h0[i] = (bf16)0.0f;
  h1[i] = (bf16)0.0f;
  if (i < 4096) bar[i] = 0;
}

// x,f fp32 -> bf16, rows permuted to sorted order, layout [t][rs][*].
__global__ __launch_bounds__(256) void conv_xf(const float* __restrict__ x,
                                               const float* __restrict__ f,
                                               const int* __restrict__ perm,
                                               bf16* __restrict__ xbf,
                                               bf16* __restrict__ fbf) {
  int t = blockIdx.x, rs = blockIdx.y, tid = threadIdx.x;
  int b = perm[rs];
  const float* xs = x + ((size_t)b * S_ + t) * UNI_;
  bf16* xd = xbf + ((size_t)t * B_ + rs) * UNI_;
  xd[tid] = (bf16)xs[tid];
  xd[tid + 256] = (bf16)xs[tid + 256];
  if (tid < FLD_) {
    fbf[((size_t)t * B_ + rs) * FLD_ + tid] =
        (bf16)f[((size_t)b * S_ + t) * FLD_ + tid];
  }
}

// zero out[b][t][:] for t >= len[b]. grid (S, B), 256 thr x float4.
__global__ __launch_bounds__(256) void zero_tail(const int* __restrict__ len,
                                                 float* __restrict__ out) {
  int t = blockIdx.x, b = blockIdx.y;
  if (t < len[b]) return;
  float4 z = {0.0f, 0.0f, 0.0f, 0.0f};
  float4* o = (float4*)(out + ((size_t)b * S_ + t) * HID_);
  o[threadIdx.x] = z;
}

// ---------------------------------------------------------------------------
// Tree grid barrier (256 blocks): 16 L1 counters (16 blocks each) -> L2
// counter (16 arrivals) -> 64 release slots. NO cache fences: all state is
// agent-scope relaxed atomics (coherent at L3). Callers drain their own
// stores (vmcnt) before arriving; root orders resets before release via
// s_waitcnt. bar ints: L1[g] at g*32 (g<16); L2 at 1024; slots 2048 + s*32.
// ---------------------------------------------------------------------------
__device__ __forceinline__ void grid_barrier(int* __restrict__ bar, int t) {
  if (threadIdx.x == 0) {
    const int g = blockIdx.x >> 4;
    int p1 = __hip_atomic_fetch_add(bar + g * 32, 1, __ATOMIC_RELAXED,
                                    __HIP_MEMORY_SCOPE_AGENT);
    bool released = false;
    if (p1 == 15) {
      int p2 = __hip_atomic_fetch_add(bar + 1024, 1, __ATOMIC_RELAXED,
                                      __HIP_MEMORY_SCOPE_AGENT);
      if (p2 == 15) {
        // all 256 arrived: reset counters, THEN release (ordered by waitcnt)
#pragma unroll
        for (int g2 = 0; g2 < 16; ++g2)
          __hip_atomic_store(bar + g2 * 32, 0, __ATOMIC_RELAXED,
                             __HIP_MEMORY_SCOPE_AGENT);
        __hip_atomic_store(bar + 1024, 0, __ATOMIC_RELAXED,
                           __HIP_MEMORY_SCOPE_AGENT);
        asm volatile("s_waitcnt vmcnt(0)" ::: "memory");
#pragma unroll
        for (int s = 0; s < NSLOT; ++s)
          __hip_atomic_store(bar + 2048 + s * 32, t + 1, __ATOMIC_RELAXED,
                             __HIP_MEMORY_SCOPE_AGENT);
        released = true;
      }
    }
    if (!released) {
      int* my = bar + 2048 + (blockIdx.x & (NSLOT - 1)) * 32;
      while (__hip_atomic_load(my, __ATOMIC_RELAXED,
                               __HIP_MEMORY_SCOPE_AGENT) <= t)
        __builtin_amdgcn_s_sleep(1);
    }
  }
  __syncthreads();
}

// ---------------------------------------------------------------------------
// Persistent LSTM kernel: all 512 timesteps.
// ---------------------------------------------------------------------------
__global__ __launch_bounds__(512, 1) void lstm_persistent(
    const bf16* __restrict__ xbf,     // [S][128][UNI] sorted rows
    const bf16* __restrict__ fbf,     // [S][128][FLD] sorted rows
    const bf16* __restrict__ W1b,     // [4H][K1]
    const bf16* __restrict__ W2b,     // [2H][FLD]
    const float* __restrict__ bias1,  // [4H]
    const float* __restrict__ bias2,  // [2H]
    bf16* __restrict__ ha,            // [128][HID] h buffer (even t reads)
    bf16* __restrict__ hb,            // [128][HID] h buffer (odd t reads)
    const int* __restrict__ perm_g,   // [128] sorted -> orig
    const int* __restrict__ lens_g,   // [128] sorted desc
    float* __restrict__ out,
    int* __restrict__ bar) {
  // B-fragments in per-lane read order: a wave's ds_read_b128 is
  // lane-contiguous (stride-1, zero bank conflicts).
  __shared__ bf16 BsF[2 * 48 * 64 * 8];  // 98304 B  W1 frags [nt][s][lane]
  __shared__ bf16 Bs2[4 * 64 * 8];       //  4096 B  W2 frags [s][lane]
  __shared__ float pre_s[64][33];        //  8448 B  [row][gr32]
  __shared__ float rd_s[64][17];         //  4352 B  [row][gr16]
  __shared__ bf16 h_pack[64][8];         //  1024 B  h staging for packers
  // total 116,224 B -> 1 block/CU; grid 256 = 256 CUs, all co-resident

  const int tid = threadIdx.x;
  const int nb = blockIdx.x;
  const int rb = nb & 1;        // row group: rows [rb*64, rb*64+64)
  const int cb = nb >> 1;       // col group: H-cols [cb*8, cb*8+8)

  // ---- one-time staging: W1 fragments ----
  for (int i = tid; i < 2 * 48 * 64; i += 512) {
    int nt = i / (48 * 64);
    int r = i - nt * (48 * 64);
    int s = r >> 6, lane = r & 63;
    int gr32 = nt * 16 + (lane & 15);             // gate-col within block
    int wrow = (gr32 >> 3) * HID_ + cb * 8 + (gr32 & 7);
    int k = s * 32 + (lane >> 4) * 8;
    *(bf16x8*)(BsF + (size_t)i * 8) = *(const bf16x8*)(W1b + (size_t)wrow * K1_ + k);
  }
  if (tid < 256) {  // W2 fragments (16 gate2-cols, K=128)
    int s = tid >> 6, lane = tid & 63;
    int gr16 = lane & 15;
    int w2row = (gr16 >> 3) * HID_ + cb * 8 + (gr16 & 7);
    int k = s * 32 + (lane >> 4) * 8;
    *(bf16x8*)(Bs2 + (size_t)tid * 8) = *(const bf16x8*)(W2b + (size_t)w2row * FLD_ + k);
  }
  __syncthreads();

  // ---- per-thread compute-phase constants ----
  const int wave = tid >> 6;
  const int lane = tid & 63;
  const int quad = lane >> 4;
  const int l16 = lane & 15;
  const int rt = wave & 3;                     // row tile within block
  const int nt = wave >> 2;                    // N tile
  const int m = rb * 64 + rt * 16 + l16;       // sorted batch row (A operand)
  const int wlen = lens_g[rb * 64 + rt * 16];  // tile max len (sorted desc)
  const bf16* bp = BsF + (size_t)nt * (48 * 64 * 8) + (size_t)lane * 8;
  const bf16* b2p = Bs2 + (size_t)lane * 8;

  // ---- update-phase mapping: thread -> (row, col) ----
  const int urow = tid >> 3;        // 0..63 (row within block)
  const int cc = tid & 7;           // col within block
  const int grow = rb * 64 + urow;  // sorted global row
  const int gcol = cb * 8 + cc;     // global H col
  const float b1i = bias1[gcol];
  const float b1j = bias1[HID_ + gcol];
  const float b1f = bias1[2 * HID_ + gcol];
  const float b1o = bias1[3 * HID_ + gcol];
  const float b2r = bias2[gcol];
  const float b2d = bias2[HID_ + gcol];
  const int ulen = lens_g[grow];
  float* outp = out + (size_t)perm_g[grow] * (S_ * HID_) + gcol;

  // packer mapping (tid < 128): 8 bytes of h each
  const int prow = tid >> 1;
  const int phalf = tid & 1;

  float c_my = 0.0f;  // cell state (thread-owned)
  float h_my = 0.0f;  // hidden state fp32 master

  for (int t = 0; t < S_; ++t) {
    const bf16* hcur = (t & 1) ? hb : ha;
    bf16* hnxt = (t & 1) ? ha : hb;

    if (t < wlen) {
      floatx4 accx = {0.f, 0.f, 0.f, 0.f};   // x part
      floatx4 acch0 = {0.f, 0.f, 0.f, 0.f};  // h part, first half
      floatx4 acch1 = {0.f, 0.f, 0.f, 0.f};  // h part, second half
      const bf16* xp = xbf + ((size_t)t * B_ + m) * UNI_ + quad * 8;
      const u64* hq = (const u64*)(hcur + (size_t)m * HID_) + quad * 2;

      // ---- K in [0,512): A = x_t (normal loads, L2-warm) ----
#pragma unroll
      for (int s = 0; s < 16; ++s) {
        bf16x8 a = *(const bf16x8*)(xp + s * 32);
        bf16x8 b = *(const bf16x8*)(bp + (size_t)s * 512);
        accx = __builtin_amdgcn_mfma_f32_16x16x32_bf16(a, b, accx, 0, 0, 0);
      }
      // ---- K in [512,1536): A = h_prev (L2-bypass coherent 8B loads) ----
#pragma unroll 8
      for (int s = 0; s < 16; ++s) {
        u64x2 u;
        u[0] = __hip_atomic_load(hq + (size_t)s * 8, __ATOMIC_RELAXED,
                                 __HIP_MEMORY_SCOPE_AGENT);
        u[1] = __hip_atomic_load(hq + (size_t)s * 8 + 1, __ATOMIC_RELAXED,
                                 __HIP_MEMORY_SCOPE_AGENT);
        bf16x8 a = __builtin_bit_cast(bf16x8, u);
        bf16x8 b = *(const bf16x8*)(bp + (size_t)(16 + s) * 512);
        acch0 = __builtin_amdgcn_mfma_f32_16x16x32_bf16(a, b, acch0, 0, 0, 0);
      }
#pragma unroll 8
      for (int s = 16; s < 32; ++s) {
        u64x2 u;
        u[0] = __hip_atomic_load(hq + (size_t)s * 8, __ATOMIC_RELAXED,
                                 __HIP_MEMORY_SCOPE_AGENT);
        u[1] = __hip_atomic_load(hq + (size_t)s * 8 + 1, __ATOMIC_RELAXED,
                                 __HIP_MEMORY_SCOPE_AGENT);
        bf16x8 a = __builtin_bit_cast(bf16x8, u);
        bf16x8 b = *(const bf16x8*)(bp + (size_t)(16 + s) * 512);
        acch1 = __builtin_amdgcn_mfma_f32_16x16x32_bf16(a, b, acch1, 0, 0, 0);
      }
      // ---- field GEMM on nt==1 waves (16 gate2-cols, K=128) ----
      if (nt) {
        floatx4 accf = {0.f, 0.f, 0.f, 0.f};
        const bf16* fp = fbf + ((size_t)t * B_ + m) * FLD_ + quad * 8;
#pragma unroll
        for (int s = 0; s < 4; ++s) {
          bf16x8 a = *(const bf16x8*)(fp + s * 32);
          bf16x8 b = *(const bf16x8*)(b2p + (size_t)s * 512);
          accf = __builtin_amdgcn_mfma_f32_16x16x32_bf16(a, b, accf, 0, 0, 0);
        }
        const int r0 = rt * 16 + quad * 4;
#pragma unroll
        for (int r = 0; r < 4; ++r) rd_s[r0 + r][l16] = accf[r];
      }
      // ---- C write: col=l16, row=quad*4+r ----
      const int r0 = rt * 16 + quad * 4;
#pragma unroll
      for (int r = 0; r < 4; ++r)
        pre_s[r0 + r][nt * 16 + l16] = accx[r] + acch0[r] + acch1[r];
    }
    __syncthreads();

    // ---- LSTM elementwise update (c, h in registers; 1 col/thread) ----
    if (t < ulen) {
      float iv = pre_s[urow][cc] + b1i;
      float jv = pre_s[urow][8 + cc] + b1j;
      float fv = pre_s[urow][16 + cc] + b1f;
      float ov = pre_s[urow][24 + cc] + b1o;
      float rv = rd_s[urow][cc] + b2r;
      float dv = rd_s[urow][8 + cc] + b2d;
      c_my = sigf(fv + 1.0f) * c_my + sigf(iv) * tanhf(jv) + sigf(rv) * tanhf(dv);
      h_my = sigf(ov) * tanhf(c_my);
      outp[(size_t)t * HID_] = h_my;
    }
    h_pack[urow][cc] = (bf16)h_my;  // unconditional (frozen rows keep old h)
    __syncthreads();

    // ---- packers: write-through h to global (L2-bypass coherent) ----
    if (tid < 128) {
      u64 val = *(const u64*)(&h_pack[prow][phalf * 4]);
      u64* dst = (u64*)(hnxt + (size_t)(rb * 64 + prow) * HID_ + cb * 8) + phalf;
      __hip_atomic_store(dst, val, __ATOMIC_RELAXED, __HIP_MEMORY_SCOPE_AGENT);
      asm volatile("s_waitcnt vmcnt(0)" ::: "memory");  // drain before arrive
    }
    __syncthreads();

    grid_barrier(bar, t);  // h globally visible (L3) before t+1 anywhere
  }

  // ---- final h, c tails (fp32 masters from registers) ----
  {
    const size_t base = (size_t)B_ * S_ * HID_;
    const size_t pr = (size_t)perm_g[grow] * HID_ + gcol;
    out[base + pr] = h_my;
    out[base + (size_t)B_ * HID_ + pr] = c_my;
  }
}

// ---------------------------------------------------------------------------
extern "C" void kernel_launch(void* const* d_in, const int* in_sizes, int n_in,
                              void* d_out, int out_size, void* d_ws, size_t ws_size,
                              hipStream_t stream) {
  const float* x = (const float*)d_in[0];
  const float* f = (const float*)d_in[1];
  const int* len = (const int*)d_in[2];
  const float* W1 = (const float*)d_in[3];
  const float* b1 = (const float*)d_in[4];
  const float* W2 = (const float*)d_in[5];
  const float* b2 = (const float*)d_in[6];
  float* out = (float*)d_out;

  char* ws = (char*)d_ws;
  bf16* W1b = (bf16*)(ws);                    // 12,582,912
  bf16* W2b = (bf16*)(ws + 12582912);         //    524,288
  bf16* xbf = (bf16*)(ws + 13107200);         // 67,108,864  [S][B][UNI]
  bf16* fbf = (bf16*)(ws + 80216064);         // 16,777,216  [S][B][FLD]
  bf16* h0 = (bf16*)(ws + 96993280);          //    262,144
  bf16* h1 = (bf16*)(ws + 97255424);          //    262,144
  int* perm = (int*)(ws + 97517568);          //        512
  int* lens = (int*)(ws + 97518080);          //        512
  int* bar = (int*)(ws + 97518592);           //     16,384 (4096 ints)
  // total ~97.5 MB

  sort_kernel<<<1, 128, 0, stream>>>(len, perm, lens);
  conv_w<<<(4096 * K1_ + 2048 * FLD_ + 255) / 256, 256, 0, stream>>>(W1, W2, W1b, W2b);
  zero_state<<<512, 256, 0, stream>>>(h0, h1, bar);
  conv_xf<<<dim3(S_, B_), 256, 0, stream>>>(x, f, perm, xbf, fbf);
  zero_tail<<<dim3(S_, B_), 256, 0, stream>>>(len, out);

  lstm_persistent<<<NBLK, 512, 0, stream>>>(xbf, fbf, W1b, W2b, b1, b2, h0, h1,
                                            perm, lens, out, bar);
}